// Round 1
// baseline (89.835 us; speedup 1.0000x reference)
//
#include <hip/hip_runtime.h>
#include <hip/hip_bf16.h>
#include <math.h>

// S4 SSKernelNPLR kernel generation, fully fused per-head:
//   phase 1: stage per-h pole data (w*dt, v=Bc*Cc outer products) in LDS
//   phase 2: Cauchy sum + Woodbury at each of 2049 rfft nodes
//            using z = 2i*tan(pi*l/L) and 2/(1+omega) = 1 + i*tan(pi*l/L)
//   phase 3: in-LDS radix-2 DIT inverse FFT (length 4096), write real part.
//
// Dims hardcoded to the reference: H=512, N=64, R=1, CH=1, L=4096.

#define HH   512
#define NN   64
#define LLEN 4096
#define LHALF 2048
#define NTHREADS 256

__global__ __launch_bounds__(NTHREADS) void ssknplr_kernel(
    const float* __restrict__ log_dt,
    const float* __restrict__ w_re, const float* __restrict__ w_im,
    const float* __restrict__ B_re, const float* __restrict__ B_im,
    const float* __restrict__ P_re, const float* __restrict__ P_im,
    const float* __restrict__ C_re, const float* __restrict__ C_im,
    float* __restrict__ out)
{
    __shared__ float s_wr[NN], s_wi[NN];
    __shared__ float s_v00r[NN], s_v00i[NN];
    __shared__ float s_v01r[NN], s_v01i[NN];
    __shared__ float s_v10r[NN], s_v10i[NN];
    __shared__ float s_v11[NN];
    __shared__ float2 X[LLEN];       // 32 KB: spectrum, then time-domain
    __shared__ float2 tw[LHALF];     // 16 KB: exp(+2*pi*i*j/4096), j<2048

    const int h   = blockIdx.x;
    const int tid = threadIdx.x;
    const float dt = expf(log_dt[h]);

    // ---- phase 1: per-head pole data ----
    if (tid < NN) {
        const int n   = tid;
        const int idx = h * NN + n;
        const float wr = w_re[idx] * dt;
        const float wi = w_im[idx] * dt;
        s_wr[n] = wr;
        s_wi[n] = wi;
        const float Br = B_re[idx], Bi = B_im[idx];
        const float Pr = P_re[idx], Pi = P_im[idx];
        const float Cr = C_re[idx], Ci = C_im[idx];
        // v00 = B*C ; v01 = B*conj(P) ; v10 = P*C ; v11 = |P|^2 (real)
        s_v00r[n] = Br * Cr - Bi * Ci;
        s_v00i[n] = Br * Ci + Bi * Cr;
        s_v01r[n] = Br * Pr + Bi * Pi;
        s_v01i[n] = Bi * Pr - Br * Pi;
        s_v10r[n] = Pr * Cr - Pi * Ci;
        s_v10i[n] = Pr * Ci + Pi * Cr;
        s_v11[n]  = Pr * Pr + Pi * Pi;
    }
    // twiddle table: tw[j] = exp(+2*pi*i*j/4096)
    const float two_pi_over_L = 6.28318530717958647692f / (float)LLEN;
    for (int j = tid; j < LHALF; j += NTHREADS) {
        float sj, cj;
        sincosf(two_pi_over_L * (float)j, &sj, &cj);
        tw[j] = make_float2(cj, sj);
    }
    __syncthreads();

    // ---- phase 2: Cauchy + Woodbury at each frequency node ----
    const float pi_over_L = 3.14159265358979323846f / (float)LLEN;
    for (int l = tid; l < LHALF; l += NTHREADS) {
        const float t  = tanf(pi_over_L * (float)l);  // z = 2*i*t
        const float t2 = 2.0f * t;
        float S00r = 0.f, S00i = 0.f;
        float S01r = 0.f, S01i = 0.f;
        float S10r = 0.f, S10i = 0.f;
        float S11r = 0.f, S11i = 0.f;
        #pragma unroll 8
        for (int n = 0; n < NN; ++n) {
            const float dre  = -s_wr[n];
            const float dim_ = t2 - s_wi[n];
            const float inv  = 1.0f / (dre * dre + dim_ * dim_);
            const float ur   = dre * inv;
            const float ui   = -dim_ * inv;
            S00r += s_v00r[n] * ur - s_v00i[n] * ui;
            S00i += s_v00r[n] * ui + s_v00i[n] * ur;
            S01r += s_v01r[n] * ur - s_v01i[n] * ui;
            S01i += s_v01r[n] * ui + s_v01i[n] * ur;
            S10r += s_v10r[n] * ur - s_v10i[n] * ui;
            S10i += s_v10r[n] * ui + s_v10i[n] * ur;
            S11r += s_v11[n] * ur;
            S11i += s_v11[n] * ui;
        }
        const float r00r = dt * S00r, r00i = dt * S00i;
        const float r01r = dt * S01r, r01i = dt * S01i;
        const float r10r = dt * S10r, r10i = dt * S10i;
        const float r11r = dt * S11r, r11i = dt * S11i;
        // corr = r01*r10 / (1 + r11)
        const float dr   = 1.0f + r11r, di = r11i;
        const float dinv = 1.0f / (dr * dr + di * di);
        const float numr = r01r * r10r - r01i * r10i;
        const float numi = r01r * r10i + r01i * r10r;
        const float cr   = (numr * dr + numi * di) * dinv;
        const float ci   = (numi * dr - numr * di) * dinv;
        const float Wr_  = r00r - cr;
        const float Wi_  = r00i - ci;
        // K = W * (1 + i*t)   [= W * 2/(1+omega)]
        const float Kr = Wr_ - t * Wi_;
        const float Ki = Wi_ + t * Wr_;
        X[l] = make_float2(Kr, Ki);
        if (l > 0) X[LLEN - l] = make_float2(Kr, -Ki);
    }
    // Nyquist bin: analytic z->inf limit, 0.5*dt*sum_n v00 (imag discarded by Re())
    if (tid == 0) {
        float sr = 0.f, si = 0.f;
        for (int n = 0; n < NN; ++n) { sr += s_v00r[n]; si += s_v00i[n]; }
        X[LHALF] = make_float2(0.5f * dt * sr, 0.5f * dt * si);
    }
    __syncthreads();

    // ---- phase 3: inverse FFT (radix-2 DIT), length 4096 ----
    // bit-reversal permutation (12 bits)
    for (int i = tid; i < LLEN; i += NTHREADS) {
        const int j = (int)(__brev((unsigned)i) >> 20);
        if (i < j) { float2 a = X[i]; X[i] = X[j]; X[j] = a; }
    }
    __syncthreads();

    for (int s = 0; s < 12; ++s) {
        const int half = 1 << s;
        for (int b = tid; b < LHALF; b += NTHREADS) {
            const int j  = b & (half - 1);
            const int i0 = ((b >> s) << (s + 1)) + j;
            const int i1 = i0 + half;
            const float2 w = tw[j << (11 - s)];
            const float2 u = X[i0];
            const float2 v = X[i1];
            const float vr = v.x * w.x - v.y * w.y;
            const float vi = v.x * w.y + v.y * w.x;
            X[i0] = make_float2(u.x + vr, u.y + vi);
            X[i1] = make_float2(u.x - vr, u.y - vi);
        }
        __syncthreads();
    }

    // ---- output: real part / L ----
    const float scale = 1.0f / (float)LLEN;
    float* o = out + (size_t)h * LLEN;
    for (int i = tid; i < LLEN; i += NTHREADS) {
        o[i] = X[i].x * scale;
    }
}

extern "C" void kernel_launch(void* const* d_in, const int* in_sizes, int n_in,
                              void* d_out, int out_size, void* d_ws, size_t ws_size,
                              hipStream_t stream) {
    const float* log_dt = (const float*)d_in[0];
    const float* w_re   = (const float*)d_in[1];
    const float* w_im   = (const float*)d_in[2];
    const float* B_re   = (const float*)d_in[3];
    const float* B_im   = (const float*)d_in[4];
    const float* P_re   = (const float*)d_in[5];
    const float* P_im   = (const float*)d_in[6];
    const float* C_re   = (const float*)d_in[7];
    const float* C_im   = (const float*)d_in[8];
    float* out = (float*)d_out;

    ssknplr_kernel<<<dim3(HH), dim3(NTHREADS), 0, stream>>>(
        log_dt, w_re, w_im, B_re, B_im, P_re, P_im, C_re, C_im, out);
}

// Round 2
// 53.308 us; speedup vs baseline: 1.6852x; 1.6852x over previous
//
#include <hip/hip_runtime.h>
#include <hip/hip_bf16.h>
#include <math.h>

// S4 SSKernelNPLR kernel generation, fully fused per-head:
//   phase 1: stage per-h pole data (w*dt, dt-scaled v=Bc*Cc outer products) in LDS
//   phase 2: Cauchy sum + Woodbury at each of 2049 rfft nodes
//            using z = 2i*tan(pi*l/L) and 2/(1+omega) = 1 + i*tan(pi*l/L)
//            loop order: pole OUTER (LDS read once), 8 freqs/thread INNER (regs)
//   phase 3: in-LDS radix-2 DIT inverse FFT (length 4096), write real part.
//
// Dims hardcoded to the reference: H=512, N=64, R=1, CH=1, L=4096.

#define HH   512
#define NN   64
#define LLEN 4096
#define LHALF 2048
#define NTHREADS 256
#define FPT 8   // frequencies per thread (LHALF / NTHREADS)

__global__ __launch_bounds__(NTHREADS) void ssknplr_kernel(
    const float* __restrict__ log_dt,
    const float* __restrict__ w_re, const float* __restrict__ w_im,
    const float* __restrict__ B_re, const float* __restrict__ B_im,
    const float* __restrict__ P_re, const float* __restrict__ P_im,
    const float* __restrict__ C_re, const float* __restrict__ C_im,
    float* __restrict__ out)
{
    // packed per-pole data (v pre-scaled by dt):
    //   p1 = (-wr, wi, v00r, v00i) ; p2 = (v01r, v01i, v10r, v10i) ; v11
    __shared__ float4 s_p1[NN];
    __shared__ float4 s_p2[NN];
    __shared__ float  s_v11[NN];
    __shared__ float2 X[LLEN];       // 32 KB: spectrum, then time-domain
    __shared__ float2 tw[LHALF];     // 16 KB: exp(+2*pi*i*j/4096), j<2048

    const int h   = blockIdx.x;
    const int tid = threadIdx.x;
    const float dt = expf(log_dt[h]);

    // ---- phase 1: per-head pole data ----
    if (tid < NN) {
        const int n   = tid;
        const int idx = h * NN + n;
        const float wr = w_re[idx] * dt;
        const float wi = w_im[idx] * dt;
        const float Br = B_re[idx], Bi = B_im[idx];
        const float Pr = P_re[idx], Pi = P_im[idx];
        const float Cr = C_re[idx], Ci = C_im[idx];
        // v00 = B*C ; v01 = B*conj(P) ; v10 = P*C ; v11 = |P|^2 (all * dt)
        s_p1[n] = make_float4(-wr, wi,
                              dt * (Br * Cr - Bi * Ci),
                              dt * (Br * Ci + Bi * Cr));
        s_p2[n] = make_float4(dt * (Br * Pr + Bi * Pi),
                              dt * (Bi * Pr - Br * Pi),
                              dt * (Pr * Cr - Pi * Ci),
                              dt * (Pr * Ci + Pi * Cr));
        s_v11[n] = dt * (Pr * Pr + Pi * Pi);
    }
    // twiddle table: tw[j] = exp(+2*pi*i*j/4096)
    const float two_pi_over_L = 6.28318530717958647692f / (float)LLEN;
    for (int j = tid; j < LHALF; j += NTHREADS) {
        float sj, cj;
        sincosf(two_pi_over_L * (float)j, &sj, &cj);
        tw[j] = make_float2(cj, sj);
    }
    __syncthreads();

    // ---- phase 2: Cauchy + Woodbury, pole-outer / freq-inner ----
    const float pi_over_L = 3.14159265358979323846f / (float)LLEN;
    float tv[FPT], t2v[FPT];
    #pragma unroll
    for (int k = 0; k < FPT; ++k) {
        const int l = tid + k * NTHREADS;
        tv[k]  = tanf(pi_over_L * (float)l);   // z = 2*i*t
        t2v[k] = 2.0f * tv[k];
    }
    float S00r[FPT], S00i[FPT], S01r[FPT], S01i[FPT];
    float S10r[FPT], S10i[FPT], S11r[FPT], S11i[FPT];
    #pragma unroll
    for (int k = 0; k < FPT; ++k) {
        S00r[k] = S00i[k] = S01r[k] = S01i[k] = 0.f;
        S10r[k] = S10i[k] = S11r[k] = S11i[k] = 0.f;
    }

    for (int n = 0; n < NN; ++n) {
        const float4 p1  = s_p1[n];   // nr, wi, v00r, v00i
        const float4 p2  = s_p2[n];   // v01r, v01i, v10r, v10i
        const float  v11 = s_v11[n];
        const float  nr  = p1.x;
        const float  wi  = p1.y;
        const float  wr2 = nr * nr;
        #pragma unroll
        for (int k = 0; k < FPT; ++k) {
            const float dim_ = t2v[k] - wi;
            const float den  = fmaf(dim_, dim_, wr2);
            const float inv  = __builtin_amdgcn_rcpf(den);
            const float ur   = nr * inv;
            const float ui   = -dim_ * inv;
            S00r[k] = fmaf(p1.z, ur, fmaf(-p1.w, ui, S00r[k]));
            S00i[k] = fmaf(p1.z, ui, fmaf( p1.w, ur, S00i[k]));
            S01r[k] = fmaf(p2.x, ur, fmaf(-p2.y, ui, S01r[k]));
            S01i[k] = fmaf(p2.x, ui, fmaf( p2.y, ur, S01i[k]));
            S10r[k] = fmaf(p2.z, ur, fmaf(-p2.w, ui, S10r[k]));
            S10i[k] = fmaf(p2.z, ui, fmaf( p2.w, ur, S10i[k]));
            S11r[k] = fmaf(v11, ur, S11r[k]);
            S11i[k] = fmaf(v11, ui, S11i[k]);
        }
    }

    #pragma unroll
    for (int k = 0; k < FPT; ++k) {
        const int l = tid + k * NTHREADS;
        // r values are the S sums (dt already folded into v)
        // corr = r01*r10 / (1 + r11)
        const float dr   = 1.0f + S11r[k], di = S11i[k];
        const float dinv = __builtin_amdgcn_rcpf(fmaf(dr, dr, di * di));
        const float numr = S01r[k] * S10r[k] - S01i[k] * S10i[k];
        const float numi = S01r[k] * S10i[k] + S01i[k] * S10r[k];
        const float cr   = (numr * dr + numi * di) * dinv;
        const float ci   = (numi * dr - numr * di) * dinv;
        const float Wr_  = S00r[k] - cr;
        const float Wi_  = S00i[k] - ci;
        // K = W * (1 + i*t)   [= W * 2/(1+omega)]
        const float t  = tv[k];
        const float Kr = fmaf(-t, Wi_, Wr_);
        const float Ki = fmaf( t, Wr_, Wi_);
        X[l] = make_float2(Kr, Ki);
        if (l > 0) X[LLEN - l] = make_float2(Kr, -Ki);
    }
    // Nyquist bin: analytic z->inf limit, 0.5*dt*sum_n v00 (v pre-scaled by dt)
    if (tid == 0) {
        float sr = 0.f, si = 0.f;
        for (int n = 0; n < NN; ++n) { sr += s_p1[n].z; si += s_p1[n].w; }
        X[LHALF] = make_float2(0.5f * sr, 0.5f * si);
    }
    __syncthreads();

    // ---- phase 3: inverse FFT (radix-2 DIT), length 4096 ----
    // bit-reversal permutation (12 bits)
    for (int i = tid; i < LLEN; i += NTHREADS) {
        const int j = (int)(__brev((unsigned)i) >> 20);
        if (i < j) { float2 a = X[i]; X[i] = X[j]; X[j] = a; }
    }
    __syncthreads();

    for (int s = 0; s < 12; ++s) {
        const int half = 1 << s;
        for (int b = tid; b < LHALF; b += NTHREADS) {
            const int j  = b & (half - 1);
            const int i0 = ((b >> s) << (s + 1)) + j;
            const int i1 = i0 + half;
            const float2 w = tw[j << (11 - s)];
            const float2 u = X[i0];
            const float2 v = X[i1];
            const float vr = v.x * w.x - v.y * w.y;
            const float vi = v.x * w.y + v.y * w.x;
            X[i0] = make_float2(u.x + vr, u.y + vi);
            X[i1] = make_float2(u.x - vr, u.y - vi);
        }
        __syncthreads();
    }

    // ---- output: real part / L ----
    const float scale = 1.0f / (float)LLEN;
    float* o = out + (size_t)h * LLEN;
    for (int i = tid; i < LLEN; i += NTHREADS) {
        o[i] = X[i].x * scale;
    }
}

extern "C" void kernel_launch(void* const* d_in, const int* in_sizes, int n_in,
                              void* d_out, int out_size, void* d_ws, size_t ws_size,
                              hipStream_t stream) {
    const float* log_dt = (const float*)d_in[0];
    const float* w_re   = (const float*)d_in[1];
    const float* w_im   = (const float*)d_in[2];
    const float* B_re   = (const float*)d_in[3];
    const float* B_im   = (const float*)d_in[4];
    const float* P_re   = (const float*)d_in[5];
    const float* P_im   = (const float*)d_in[6];
    const float* C_re   = (const float*)d_in[7];
    const float* C_im   = (const float*)d_in[8];
    float* out = (float*)d_out;

    ssknplr_kernel<<<dim3(HH), dim3(NTHREADS), 0, stream>>>(
        log_dt, w_re, w_im, B_re, B_im, P_re, P_im, C_re, C_im, out);
}

// Round 3
// 48.743 us; speedup vs baseline: 1.8431x; 1.0937x over previous
//
#include <hip/hip_runtime.h>
#include <hip/hip_bf16.h>
#include <math.h>

// S4 SSKernelNPLR, fused per-head:
//   phase 1: stage per-h pole data (w*dt, dt-scaled v=Bc*Cc products) in LDS
//   phase 2: Cauchy sum + Woodbury at 2049 rfft nodes (z = 2i*tan(pi*l/L))
//   phase 2.5: Hermitian recombination -> half-size complex spectrum Z[0..2047]
//   phase 3: in-LDS 2048-pt radix-2 DIF inverse FFT (natural in, bitrev out)
//   output: x[2m]=Re z[m]/M, x[2m+1]=Im z[m]/M, coalesced float2 stores.
//
// LDS index padding ZPAD kills stride-2^k bank conflicts; twiddles are
// stage-major (stage s at base 2^s-1, j consecutive) so reads are stride-1.
//
// Dims hardcoded: H=512, N=64, R=1, CH=1, L=4096.

#define HH   512
#define NN   64
#define LLEN 4096
#define MM   2048      // half length
#define NTHREADS 256
#define FPT  8         // freq bins per thread in phase 2 (MM/NTHREADS)
#define ZPAD(i) ((i) + ((i) >> 4))

__global__ __launch_bounds__(NTHREADS) void ssknplr_kernel(
    const float* __restrict__ log_dt,
    const float* __restrict__ w_re, const float* __restrict__ w_im,
    const float* __restrict__ B_re, const float* __restrict__ B_im,
    const float* __restrict__ P_re, const float* __restrict__ P_im,
    const float* __restrict__ C_re, const float* __restrict__ C_im,
    float* __restrict__ out)
{
    // packed per-pole data (v pre-scaled by dt):
    //   p1 = (-wr, wi, v00r, v00i) ; p2 = (v01r, v01i, v10r, v10i) ; v11
    __shared__ float4 s_p1[NN];
    __shared__ float4 s_p2[NN];
    __shared__ float  s_v11[NN];
    __shared__ float2 s_Z[ZPAD(MM) + 1];   // padded spectrum/workspace (~17.4 KB)
    __shared__ float2 s_tw[MM];            // stage-major twiddles (16 KB)

    const int h   = blockIdx.x;
    const int tid = threadIdx.x;
    const float dt = expf(log_dt[h]);

    // ---- phase 1: per-head pole data ----
    if (tid < NN) {
        const int n   = tid;
        const int idx = h * NN + n;
        const float wr = w_re[idx] * dt;
        const float wi = w_im[idx] * dt;
        const float Br = B_re[idx], Bi = B_im[idx];
        const float Pr = P_re[idx], Pi = P_im[idx];
        const float Cr = C_re[idx], Ci = C_im[idx];
        s_p1[n] = make_float4(-wr, wi,
                              dt * (Br * Cr - Bi * Ci),
                              dt * (Br * Ci + Bi * Cr));
        s_p2[n] = make_float4(dt * (Br * Pr + Bi * Pi),
                              dt * (Bi * Pr - Br * Pi),
                              dt * (Pr * Cr - Pi * Ci),
                              dt * (Pr * Ci + Pi * Cr));
        s_v11[n] = dt * (Pr * Pr + Pi * Pi);
    }
    // stage-major twiddles: entry (2^s - 1) + j holds e^{+2*pi*i*j / 2^{s+1}}
    for (int i = tid; i < MM - 1; i += NTHREADS) {
        const int v = i + 1;
        const int s = 31 - __clz(v);
        const int j = v - (1 << s);
        const float ang = (float)j * (3.14159265358979323846f / (float)(1 << s));
        float sj, cj;
        sincosf(ang, &sj, &cj);
        s_tw[i] = make_float2(cj, sj);
    }
    __syncthreads();

    // ---- phase 2: Cauchy + Woodbury, pole-outer / freq-inner ----
    const float pi_over_L = 3.14159265358979323846f / (float)LLEN;
    float tv[FPT], t2v[FPT];
    #pragma unroll
    for (int k = 0; k < FPT; ++k) {
        const int l = tid + k * NTHREADS;
        tv[k]  = tanf(pi_over_L * (float)l);   // z = 2*i*t
        t2v[k] = 2.0f * tv[k];
    }
    float S00r[FPT], S00i[FPT], S01r[FPT], S01i[FPT];
    float S10r[FPT], S10i[FPT], S11r[FPT], S11i[FPT];
    #pragma unroll
    for (int k = 0; k < FPT; ++k) {
        S00r[k] = S00i[k] = S01r[k] = S01i[k] = 0.f;
        S10r[k] = S10i[k] = S11r[k] = S11i[k] = 0.f;
    }

    for (int n = 0; n < NN; ++n) {
        const float4 p1  = s_p1[n];   // nr, wi, v00r, v00i
        const float4 p2  = s_p2[n];   // v01r, v01i, v10r, v10i
        const float  v11 = s_v11[n];
        const float  nr  = p1.x;
        const float  wi  = p1.y;
        const float  wr2 = nr * nr;
        #pragma unroll
        for (int k = 0; k < FPT; ++k) {
            const float dim_ = t2v[k] - wi;
            const float den  = fmaf(dim_, dim_, wr2);
            const float inv  = __builtin_amdgcn_rcpf(den);
            const float ur   = nr * inv;
            const float ui   = -dim_ * inv;
            S00r[k] = fmaf(p1.z, ur, fmaf(-p1.w, ui, S00r[k]));
            S00i[k] = fmaf(p1.z, ui, fmaf( p1.w, ur, S00i[k]));
            S01r[k] = fmaf(p2.x, ur, fmaf(-p2.y, ui, S01r[k]));
            S01i[k] = fmaf(p2.x, ui, fmaf( p2.y, ur, S01i[k]));
            S10r[k] = fmaf(p2.z, ur, fmaf(-p2.w, ui, S10r[k]));
            S10i[k] = fmaf(p2.z, ui, fmaf( p2.w, ur, S10i[k]));
            S11r[k] = fmaf(v11, ur, S11r[k]);
            S11i[k] = fmaf(v11, ui, S11i[k]);
        }
    }

    #pragma unroll
    for (int k = 0; k < FPT; ++k) {
        const int l = tid + k * NTHREADS;
        // corr = r01*r10 / (1 + r11)   (dt already folded into v)
        const float dr   = 1.0f + S11r[k], di = S11i[k];
        const float dinv = __builtin_amdgcn_rcpf(fmaf(dr, dr, di * di));
        const float numr = S01r[k] * S10r[k] - S01i[k] * S10i[k];
        const float numi = S01r[k] * S10i[k] + S01i[k] * S10r[k];
        const float cr   = (numr * dr + numi * di) * dinv;
        const float ci   = (numi * dr - numr * di) * dinv;
        const float Wr_  = S00r[k] - cr;
        const float Wi_  = S00i[k] - ci;
        // K = W * (1 + i*t)   [= W * 2/(1+omega)]
        const float t  = tv[k];
        const float Kr = fmaf(-t, Wi_, Wr_);
        const float Ki = fmaf( t, Wr_, Wi_);
        // l==0: target uses Re(K0) only (imag cancels in the real output)
        s_Z[ZPAD(l)] = make_float2(Kr, (l == 0) ? 0.0f : Ki);
    }
    // Nyquist bin K[M]: analytic z->inf limit, real part only
    if (tid == 0) {
        float sr = 0.f;
        for (int n = 0; n < NN; ++n) sr += s_p1[n].z;
        s_Z[ZPAD(MM)] = make_float2(0.5f * sr, 0.0f);
    }
    __syncthreads();

    // ---- phase 2.5: Hermitian recombination -> half-size spectrum (in place) ----
    // Z[k]    = (Pr - a, Pi + b),  Z[M-k] = (Pr + a, b - Pi)
    // P=(K[k]+conj(K[M-k]))/2, D=(K[k]-conj(K[M-k]))/2, e=e^{2pi i k/L},
    // a = e.s*Dr + e.c*Di, b = e.c*Dr - e.s*Di
    const float ang0 = 3.14159265358979323846f / (float)MM;   // 2*pi/L
    #pragma unroll
    for (int q = 0; q < 4; ++q) {
        const int k = tid + q * NTHREADS;     // 0..1023
        if (k == 0) {
            const float a = s_Z[ZPAD(0)].x;
            const float b = s_Z[ZPAD(MM)].x;
            s_Z[ZPAD(0)] = make_float2(0.5f * (a + b), 0.5f * (a - b));
            const float2 km = s_Z[ZPAD(MM / 2)];
            s_Z[ZPAD(MM / 2)] = make_float2(km.x, -km.y);
        } else {
            const float2 Ka = s_Z[ZPAD(k)];
            const float2 Kb = s_Z[ZPAD(MM - k)];
            float sk, ck;
            sincosf((float)k * ang0, &sk, &ck);
            const float Pr = 0.5f * (Ka.x + Kb.x), Pi = 0.5f * (Ka.y - Kb.y);
            const float Dr = 0.5f * (Ka.x - Kb.x), Di = 0.5f * (Ka.y + Kb.y);
            const float al = sk * Dr + ck * Di;
            const float be = ck * Dr - sk * Di;
            s_Z[ZPAD(k)]      = make_float2(Pr - al, Pi + be);
            s_Z[ZPAD(MM - k)] = make_float2(Pr + al, be - Pi);
        }
    }
    __syncthreads();

    // ---- phase 3: 2048-pt inverse FFT, radix-2 DIF (natural in, bitrev out) ----
    for (int s = 10; s >= 0; --s) {
        const int half = 1 << s;
        #pragma unroll
        for (int q = 0; q < 4; ++q) {
            const int b  = tid + q * NTHREADS;        // 0..1023
            const int j  = b & (half - 1);
            const int i0 = ((b >> s) << (s + 1)) + j;
            const int i1 = i0 + half;
            const float2 w = s_tw[(half - 1) + j];
            const float2 u = s_Z[ZPAD(i0)];
            const float2 v = s_Z[ZPAD(i1)];
            s_Z[ZPAD(i0)] = make_float2(u.x + v.x, u.y + v.y);
            const float dx = u.x - v.x, dy = u.y - v.y;
            s_Z[ZPAD(i1)] = make_float2(dx * w.x - dy * w.y, dx * w.y + dy * w.x);
        }
        __syncthreads();
    }

    // ---- output: z[m] = Zfinal[bitrev(m)]; x[2m]=Re/M, x[2m+1]=Im/M ----
    const float scale = 1.0f / (float)MM;
    float2* o2 = (float2*)out + (size_t)h * MM;
    #pragma unroll
    for (int q = 0; q < FPT; ++q) {
        const int m = tid + q * NTHREADS;
        const int r = (int)(__brev((unsigned)m) >> 21);
        const float2 z = s_Z[ZPAD(r)];
        o2[m] = make_float2(z.x * scale, z.y * scale);
    }
}

extern "C" void kernel_launch(void* const* d_in, const int* in_sizes, int n_in,
                              void* d_out, int out_size, void* d_ws, size_t ws_size,
                              hipStream_t stream) {
    const float* log_dt = (const float*)d_in[0];
    const float* w_re   = (const float*)d_in[1];
    const float* w_im   = (const float*)d_in[2];
    const float* B_re   = (const float*)d_in[3];
    const float* B_im   = (const float*)d_in[4];
    const float* P_re   = (const float*)d_in[5];
    const float* P_im   = (const float*)d_in[6];
    const float* C_re   = (const float*)d_in[7];
    const float* C_im   = (const float*)d_in[8];
    float* out = (float*)d_out;

    ssknplr_kernel<<<dim3(HH), dim3(NTHREADS), 0, stream>>>(
        log_dt, w_re, w_im, B_re, B_im, P_re, P_im, C_re, C_im, out);
}

// Round 4
// 44.022 us; speedup vs baseline: 2.0407x; 1.1072x over previous
//
#include <hip/hip_runtime.h>
#include <hip/hip_bf16.h>
#include <math.h>

// S4 SSKernelNPLR, fused per-head:
//   phase 1: stage per-h pole data (w*dt, dt-scaled v=Bc*Cc products) in LDS
//   phase 2: Cauchy sum + Woodbury at 2049 rfft nodes (z = 2i*tan(pi*l/L))
//   phase 2.5: Hermitian recombination -> half-size complex spectrum Z[0..2047]
//   phase 3: in-LDS 2048-pt radix-2 DIF inverse FFT (natural in, bitrev out)
//   output: x[2m]=Re z[m]/M, x[2m+1]=Im z[m]/M, coalesced float2 stores.
//
// 1024 threads/block: grid 512 -> 2 blocks/CU -> 32 waves/CU (100% occupancy
// cap) for latency hiding; __launch_bounds__(1024,8) holds VGPR <= 64.
// ZPAD index padding kills stride-2^k bank conflicts; twiddles stage-major.
//
// Dims hardcoded: H=512, N=64, R=1, CH=1, L=4096.

#define HH   512
#define NN   64
#define LLEN 4096
#define MM   2048      // half length
#define NTHREADS 1024
#define FPT  2         // freq bins per thread in phase 2 (MM/NTHREADS)
#define ZPAD(i) ((i) + ((i) >> 4))

__global__ __launch_bounds__(NTHREADS, 8) void ssknplr_kernel(
    const float* __restrict__ log_dt,
    const float* __restrict__ w_re, const float* __restrict__ w_im,
    const float* __restrict__ B_re, const float* __restrict__ B_im,
    const float* __restrict__ P_re, const float* __restrict__ P_im,
    const float* __restrict__ C_re, const float* __restrict__ C_im,
    float* __restrict__ out)
{
    // packed per-pole data (v pre-scaled by dt):
    //   p1 = (-wr, wi, v00r, v00i) ; p2 = (v01r, v01i, v10r, v10i) ; v11
    __shared__ float4 s_p1[NN];
    __shared__ float4 s_p2[NN];
    __shared__ float  s_v11[NN];
    __shared__ float2 s_Z[ZPAD(MM) + 1];   // padded spectrum/workspace (~17.4 KB)
    __shared__ float2 s_tw[MM];            // stage-major twiddles (16 KB)

    const int h   = blockIdx.x;
    const int tid = threadIdx.x;
    const float dt = expf(log_dt[h]);

    // ---- phase 1: per-head pole data ----
    if (tid < NN) {
        const int n   = tid;
        const int idx = h * NN + n;
        const float wr = w_re[idx] * dt;
        const float wi = w_im[idx] * dt;
        const float Br = B_re[idx], Bi = B_im[idx];
        const float Pr = P_re[idx], Pi = P_im[idx];
        const float Cr = C_re[idx], Ci = C_im[idx];
        s_p1[n] = make_float4(-wr, wi,
                              dt * (Br * Cr - Bi * Ci),
                              dt * (Br * Ci + Bi * Cr));
        s_p2[n] = make_float4(dt * (Br * Pr + Bi * Pi),
                              dt * (Bi * Pr - Br * Pi),
                              dt * (Pr * Cr - Pi * Ci),
                              dt * (Pr * Ci + Pi * Cr));
        s_v11[n] = dt * (Pr * Pr + Pi * Pi);
    }
    // stage-major twiddles: entry (2^s - 1) + j holds e^{+2*pi*i*j / 2^{s+1}}
    for (int i = tid; i < MM - 1; i += NTHREADS) {
        const int v = i + 1;
        const int s = 31 - __clz(v);
        const int j = v - (1 << s);
        const float ang = (float)j * (3.14159265358979323846f / (float)(1 << s));
        float sj, cj;
        sincosf(ang, &sj, &cj);
        s_tw[i] = make_float2(cj, sj);
    }
    __syncthreads();

    // ---- phase 2: Cauchy + Woodbury, pole-outer / freq-inner ----
    const float pi_over_L = 3.14159265358979323846f / (float)LLEN;
    float tv[FPT], t2v[FPT];
    #pragma unroll
    for (int k = 0; k < FPT; ++k) {
        const int l = tid + k * NTHREADS;
        tv[k]  = tanf(pi_over_L * (float)l);   // z = 2*i*t
        t2v[k] = 2.0f * tv[k];
    }
    float S00r[FPT], S00i[FPT], S01r[FPT], S01i[FPT];
    float S10r[FPT], S10i[FPT], S11r[FPT], S11i[FPT];
    #pragma unroll
    for (int k = 0; k < FPT; ++k) {
        S00r[k] = S00i[k] = S01r[k] = S01i[k] = 0.f;
        S10r[k] = S10i[k] = S11r[k] = S11i[k] = 0.f;
    }

    for (int n = 0; n < NN; ++n) {
        const float4 p1  = s_p1[n];   // nr, wi, v00r, v00i
        const float4 p2  = s_p2[n];   // v01r, v01i, v10r, v10i
        const float  v11 = s_v11[n];
        const float  nr  = p1.x;
        const float  wi  = p1.y;
        const float  wr2 = nr * nr;
        #pragma unroll
        for (int k = 0; k < FPT; ++k) {
            const float dim_ = t2v[k] - wi;
            const float den  = fmaf(dim_, dim_, wr2);
            const float inv  = __builtin_amdgcn_rcpf(den);
            const float ur   = nr * inv;
            const float ui   = -dim_ * inv;
            S00r[k] = fmaf(p1.z, ur, fmaf(-p1.w, ui, S00r[k]));
            S00i[k] = fmaf(p1.z, ui, fmaf( p1.w, ur, S00i[k]));
            S01r[k] = fmaf(p2.x, ur, fmaf(-p2.y, ui, S01r[k]));
            S01i[k] = fmaf(p2.x, ui, fmaf( p2.y, ur, S01i[k]));
            S10r[k] = fmaf(p2.z, ur, fmaf(-p2.w, ui, S10r[k]));
            S10i[k] = fmaf(p2.z, ui, fmaf( p2.w, ur, S10i[k]));
            S11r[k] = fmaf(v11, ur, S11r[k]);
            S11i[k] = fmaf(v11, ui, S11i[k]);
        }
    }

    #pragma unroll
    for (int k = 0; k < FPT; ++k) {
        const int l = tid + k * NTHREADS;
        // corr = r01*r10 / (1 + r11)   (dt already folded into v)
        const float dr   = 1.0f + S11r[k], di = S11i[k];
        const float dinv = __builtin_amdgcn_rcpf(fmaf(dr, dr, di * di));
        const float numr = S01r[k] * S10r[k] - S01i[k] * S10i[k];
        const float numi = S01r[k] * S10i[k] + S01i[k] * S10r[k];
        const float cr   = (numr * dr + numi * di) * dinv;
        const float ci   = (numi * dr - numr * di) * dinv;
        const float Wr_  = S00r[k] - cr;
        const float Wi_  = S00i[k] - ci;
        // K = W * (1 + i*t)   [= W * 2/(1+omega)]
        const float t  = tv[k];
        const float Kr = fmaf(-t, Wi_, Wr_);
        const float Ki = fmaf( t, Wr_, Wi_);
        // l==0: target uses Re(K0) only (imag cancels in the real output)
        s_Z[ZPAD(l)] = make_float2(Kr, (l == 0) ? 0.0f : Ki);
    }
    // Nyquist bin K[M]: analytic z->inf limit, real part only
    if (tid == 0) {
        float sr = 0.f;
        for (int n = 0; n < NN; ++n) sr += s_p1[n].z;
        s_Z[ZPAD(MM)] = make_float2(0.5f * sr, 0.0f);
    }
    __syncthreads();

    // ---- phase 2.5: Hermitian recombination -> half-size spectrum (in place) ----
    // Z[k]    = (Pr - a, Pi + b),  Z[M-k] = (Pr + a, b - Pi)
    // P=(K[k]+conj(K[M-k]))/2, D=(K[k]-conj(K[M-k]))/2, e=e^{2pi i k/L},
    // a = e.s*Dr + e.c*Di, b = e.c*Dr - e.s*Di
    {
        const float ang0 = 3.14159265358979323846f / (float)MM;   // 2*pi/L
        const int k = tid;                    // 0..1023
        if (k == 0) {
            const float a = s_Z[ZPAD(0)].x;
            const float b = s_Z[ZPAD(MM)].x;
            s_Z[ZPAD(0)] = make_float2(0.5f * (a + b), 0.5f * (a - b));
            const float2 km = s_Z[ZPAD(MM / 2)];
            s_Z[ZPAD(MM / 2)] = make_float2(km.x, -km.y);
        } else {
            const float2 Ka = s_Z[ZPAD(k)];
            const float2 Kb = s_Z[ZPAD(MM - k)];
            float sk, ck;
            sincosf((float)k * ang0, &sk, &ck);
            const float Pr = 0.5f * (Ka.x + Kb.x), Pi = 0.5f * (Ka.y - Kb.y);
            const float Dr = 0.5f * (Ka.x - Kb.x), Di = 0.5f * (Ka.y + Kb.y);
            const float al = sk * Dr + ck * Di;
            const float be = ck * Dr - sk * Di;
            s_Z[ZPAD(k)]      = make_float2(Pr - al, Pi + be);
            s_Z[ZPAD(MM - k)] = make_float2(Pr + al, be - Pi);
        }
    }
    __syncthreads();

    // ---- phase 3: 2048-pt inverse FFT, radix-2 DIF (natural in, bitrev out) ----
    for (int s = 10; s >= 1; --s) {
        const int half = 1 << s;
        const int b  = tid;                       // 0..1023, one butterfly each
        const int j  = b & (half - 1);
        const int i0 = ((b >> s) << (s + 1)) + j;
        const int i1 = i0 + half;
        const float2 w = s_tw[(half - 1) + j];
        const float2 u = s_Z[ZPAD(i0)];
        const float2 v = s_Z[ZPAD(i1)];
        s_Z[ZPAD(i0)] = make_float2(u.x + v.x, u.y + v.y);
        const float dx = u.x - v.x, dy = u.y - v.y;
        s_Z[ZPAD(i1)] = make_float2(dx * w.x - dy * w.y, dx * w.y + dy * w.x);
        __syncthreads();
    }
    {   // final stage s=0: twiddle = 1, pure add/sub
        const int i0 = tid << 1, i1 = i0 | 1;
        const float2 u = s_Z[ZPAD(i0)];
        const float2 v = s_Z[ZPAD(i1)];
        s_Z[ZPAD(i0)] = make_float2(u.x + v.x, u.y + v.y);
        s_Z[ZPAD(i1)] = make_float2(u.x - v.x, u.y - v.y);
    }
    __syncthreads();

    // ---- output: z[m] = Zfinal[bitrev(m)]; x[2m]=Re/M, x[2m+1]=Im/M ----
    const float scale = 1.0f / (float)MM;
    float2* o2 = (float2*)out + (size_t)h * MM;
    #pragma unroll
    for (int q = 0; q < FPT; ++q) {
        const int m = tid + q * NTHREADS;
        const int r = (int)(__brev((unsigned)m) >> 21);
        const float2 z = s_Z[ZPAD(r)];
        o2[m] = make_float2(z.x * scale, z.y * scale);
    }
}

extern "C" void kernel_launch(void* const* d_in, const int* in_sizes, int n_in,
                              void* d_out, int out_size, void* d_ws, size_t ws_size,
                              hipStream_t stream) {
    const float* log_dt = (const float*)d_in[0];
    const float* w_re   = (const float*)d_in[1];
    const float* w_im   = (const float*)d_in[2];
    const float* B_re   = (const float*)d_in[3];
    const float* B_im   = (const float*)d_in[4];
    const float* P_re   = (const float*)d_in[5];
    const float* P_im   = (const float*)d_in[6];
    const float* C_re   = (const float*)d_in[7];
    const float* C_im   = (const float*)d_in[8];
    float* out = (float*)d_out;

    ssknplr_kernel<<<dim3(HH), dim3(NTHREADS), 0, stream>>>(
        log_dt, w_re, w_im, B_re, B_im, P_re, P_im, C_re, C_im, out);
}

// Round 5
// 39.592 us; speedup vs baseline: 2.2690x; 1.1119x over previous
//
#include <hip/hip_runtime.h>
#include <hip/hip_bf16.h>
#include <math.h>

// S4 SSKernelNPLR, fused per-head:
//   phase 1: per-h pole data -> LDS, each scalar pre-DUPLICATED as float2 so
//            phase 2 operands are <2 x float> vector loads (ds_read_b64)
//   phase 2: Cauchy + Woodbury at 2049 rfft nodes, PACKED fp32 (v_pk_fma_f32):
//            each thread computes bins (tid, tid+1024) in the two halves of
//            v2f registers. z = 2i*tan(pi*l/L); 2/(1+omega) = 1 + i*tan(...).
//   phase 2.5: Hermitian recombination -> half-size complex spectrum Z[0..2047]
//   phase 3: in-LDS 2048-pt radix-2 DIF inverse FFT (natural in, bitrev out)
//   output: x[2m]=Re z[m]/M, x[2m+1]=Im z[m]/M, coalesced float2 stores.
//
// 1024 thr/block, 2 blocks/CU, __launch_bounds__(1024,8) keeps VGPR <= 64.
// ZPAD kills stride-2^k bank conflicts; twiddles stage-major (stride-1 reads).
// Dims hardcoded: H=512, N=64, R=1, CH=1, L=4096.

#define HH   512
#define NN   64
#define LLEN 4096
#define MM   2048      // half length
#define NTHREADS 1024
#define ZPAD(i) ((i) + ((i) >> 4))

typedef float v2f __attribute__((ext_vector_type(2)));

__global__ __launch_bounds__(NTHREADS, 8) void ssknplr_kernel(
    const float* __restrict__ log_dt,
    const float* __restrict__ w_re, const float* __restrict__ w_im,
    const float* __restrict__ B_re, const float* __restrict__ B_im,
    const float* __restrict__ P_re, const float* __restrict__ P_im,
    const float* __restrict__ C_re, const float* __restrict__ C_im,
    float* __restrict__ out)
{
    // per-pole duplicated scalars: [0]=-wi [1]=-wr [2]=wr^2
    // [3]=v00r [4]=v00i [5]=v01r [6]=v01i [7]=v10r [8]=v10i [9]=v11  (all *dt)
    __shared__ v2f    s_pp[NN][10];
    __shared__ float2 s_Z[ZPAD(MM) + 1];   // padded spectrum (~17.4 KB)
    __shared__ float2 s_tw[MM];            // stage-major twiddles (16 KB)

    const int h   = blockIdx.x;
    const int tid = threadIdx.x;
    const float dt = expf(log_dt[h]);

    // ---- phase 1: per-head pole data (duplicated halves) ----
    if (tid < NN) {
        const int n   = tid;
        const int idx = h * NN + n;
        const float wr = w_re[idx] * dt;
        const float wi = w_im[idx] * dt;
        const float Br = B_re[idx], Bi = B_im[idx];
        const float Pr = P_re[idx], Pi = P_im[idx];
        const float Cr = C_re[idx], Ci = C_im[idx];
        const float vals[10] = {
            -wi, -wr, wr * wr,
            dt * (Br * Cr - Bi * Ci),   // v00r
            dt * (Br * Ci + Bi * Cr),   // v00i
            dt * (Br * Pr + Bi * Pi),   // v01r  (B*conj(P))
            dt * (Bi * Pr - Br * Pi),   // v01i
            dt * (Pr * Cr - Pi * Ci),   // v10r
            dt * (Pr * Ci + Pi * Cr),   // v10i
            dt * (Pr * Pr + Pi * Pi)    // v11
        };
        #pragma unroll
        for (int j = 0; j < 10; ++j) s_pp[n][j] = (v2f){vals[j], vals[j]};
    }
    // stage-major twiddles: entry (2^s - 1) + j holds e^{+2*pi*i*j / 2^{s+1}}
    for (int i = tid; i < MM - 1; i += NTHREADS) {
        const int v = i + 1;
        const int s = 31 - __clz(v);
        const int j = v - (1 << s);
        const float ang = (float)j * (3.14159265358979323846f / (float)(1 << s));
        float sj, cj;
        sincosf(ang, &sj, &cj);
        s_tw[i] = make_float2(cj, sj);
    }
    __syncthreads();

    // ---- phase 2: Cauchy + Woodbury, packed over bins (tid, tid+1024) ----
    const float pi_over_L = 3.14159265358979323846f / (float)LLEN;
    v2f tv;
    tv.x = tanf(pi_over_L * (float)tid);
    tv.y = tanf(pi_over_L * (float)(tid + MM / 2));
    const v2f t2v = tv + tv;

    v2f a00r = 0.f, a00i = 0.f, a01r = 0.f, a01i = 0.f;
    v2f a10r = 0.f, a10i = 0.f, a11r = 0.f, a11i = 0.f;

    for (int n = 0; n < NN; ++n) {
        const v2f mwi = s_pp[n][0];
        const v2f nr  = s_pp[n][1];
        const v2f wr2 = s_pp[n][2];
        const v2f dim = t2v + mwi;
        const v2f den = __builtin_elementwise_fma(dim, dim, wr2);
        v2f inv;
        inv.x = __builtin_amdgcn_rcpf(den.x);
        inv.y = __builtin_amdgcn_rcpf(den.y);
        const v2f ur = nr * inv;
        const v2f ui = -(dim * inv);
        const v2f v00r = s_pp[n][3], v00i = s_pp[n][4];
        const v2f v01r = s_pp[n][5], v01i = s_pp[n][6];
        const v2f v10r = s_pp[n][7], v10i = s_pp[n][8];
        const v2f v11  = s_pp[n][9];
        a00r = __builtin_elementwise_fma( v00r, ur, a00r);
        a00r = __builtin_elementwise_fma(-v00i, ui, a00r);
        a00i = __builtin_elementwise_fma( v00r, ui, a00i);
        a00i = __builtin_elementwise_fma( v00i, ur, a00i);
        a01r = __builtin_elementwise_fma( v01r, ur, a01r);
        a01r = __builtin_elementwise_fma(-v01i, ui, a01r);
        a01i = __builtin_elementwise_fma( v01r, ui, a01i);
        a01i = __builtin_elementwise_fma( v01i, ur, a01i);
        a10r = __builtin_elementwise_fma( v10r, ur, a10r);
        a10r = __builtin_elementwise_fma(-v10i, ui, a10r);
        a10i = __builtin_elementwise_fma( v10r, ui, a10i);
        a10i = __builtin_elementwise_fma( v10i, ur, a10i);
        a11r = __builtin_elementwise_fma( v11,  ur, a11r);
        a11i = __builtin_elementwise_fma( v11,  ui, a11i);
    }

    {   // Woodbury + bilinear factor, packed; unpack on store.
        const v2f dr = a11r + 1.0f;
        const v2f di = a11i;
        const v2f dd = __builtin_elementwise_fma(dr, dr, di * di);
        v2f dinv;
        dinv.x = __builtin_amdgcn_rcpf(dd.x);
        dinv.y = __builtin_amdgcn_rcpf(dd.y);
        const v2f numr = a01r * a10r - a01i * a10i;
        const v2f numi = a01r * a10i + a01i * a10r;
        const v2f cr = (numr * dr + numi * di) * dinv;
        const v2f ci = (numi * dr - numr * di) * dinv;
        const v2f Wr = a00r - cr;
        const v2f Wi = a00i - ci;
        const v2f Kr = __builtin_elementwise_fma(-tv, Wi, Wr);
        const v2f Ki = __builtin_elementwise_fma( tv, Wr, Wi);
        // bin l=0: imaginary part unused in the real output
        s_Z[ZPAD(tid)] = make_float2(Kr.x, (tid == 0) ? 0.0f : Ki.x);
        s_Z[ZPAD(tid + MM / 2)] = make_float2(Kr.y, Ki.y);
    }
    // Nyquist bin K[M]: analytic z->inf limit, real part only
    if (tid == 0) {
        float sr = 0.f;
        for (int n = 0; n < NN; ++n) sr += s_pp[n][3].x;
        s_Z[ZPAD(MM)] = make_float2(0.5f * sr, 0.0f);
    }
    __syncthreads();

    // ---- phase 2.5: Hermitian recombination -> half-size spectrum (in place) ----
    {
        const float ang0 = 3.14159265358979323846f / (float)MM;   // 2*pi/L
        const int k = tid;                    // 0..1023
        if (k == 0) {
            const float a = s_Z[ZPAD(0)].x;
            const float b = s_Z[ZPAD(MM)].x;
            s_Z[ZPAD(0)] = make_float2(0.5f * (a + b), 0.5f * (a - b));
            const float2 km = s_Z[ZPAD(MM / 2)];
            s_Z[ZPAD(MM / 2)] = make_float2(km.x, -km.y);
        } else {
            const float2 Ka = s_Z[ZPAD(k)];
            const float2 Kb = s_Z[ZPAD(MM - k)];
            float sk, ck;
            sincosf((float)k * ang0, &sk, &ck);
            const float Pr = 0.5f * (Ka.x + Kb.x), Pi = 0.5f * (Ka.y - Kb.y);
            const float Dr = 0.5f * (Ka.x - Kb.x), Di = 0.5f * (Ka.y + Kb.y);
            const float al = sk * Dr + ck * Di;
            const float be = ck * Dr - sk * Di;
            s_Z[ZPAD(k)]      = make_float2(Pr - al, Pi + be);
            s_Z[ZPAD(MM - k)] = make_float2(Pr + al, be - Pi);
        }
    }
    __syncthreads();

    // ---- phase 3: 2048-pt inverse FFT, radix-2 DIF (natural in, bitrev out) ----
    for (int s = 10; s >= 1; --s) {
        const int half = 1 << s;
        const int b  = tid;                       // one butterfly per thread
        const int j  = b & (half - 1);
        const int i0 = ((b >> s) << (s + 1)) + j;
        const int i1 = i0 + half;
        const float2 w = s_tw[(half - 1) + j];
        const float2 u = s_Z[ZPAD(i0)];
        const float2 v = s_Z[ZPAD(i1)];
        s_Z[ZPAD(i0)] = make_float2(u.x + v.x, u.y + v.y);
        const float dx = u.x - v.x, dy = u.y - v.y;
        s_Z[ZPAD(i1)] = make_float2(dx * w.x - dy * w.y, dx * w.y + dy * w.x);
        __syncthreads();
    }
    {   // final stage s=0: twiddle = 1, pure add/sub
        const int i0 = tid << 1, i1 = i0 | 1;
        const float2 u = s_Z[ZPAD(i0)];
        const float2 v = s_Z[ZPAD(i1)];
        s_Z[ZPAD(i0)] = make_float2(u.x + v.x, u.y + v.y);
        s_Z[ZPAD(i1)] = make_float2(u.x - v.x, u.y - v.y);
    }
    __syncthreads();

    // ---- output: z[m] = Zfinal[bitrev(m)]; x[2m]=Re/M, x[2m+1]=Im/M ----
    const float scale = 1.0f / (float)MM;
    float2* o2 = (float2*)out + (size_t)h * MM;
    #pragma unroll
    for (int q = 0; q < 2; ++q) {
        const int m = tid + q * NTHREADS;
        const int r = (int)(__brev((unsigned)m) >> 21);
        const float2 z = s_Z[ZPAD(r)];
        o2[m] = make_float2(z.x * scale, z.y * scale);
    }
}

extern "C" void kernel_launch(void* const* d_in, const int* in_sizes, int n_in,
                              void* d_out, int out_size, void* d_ws, size_t ws_size,
                              hipStream_t stream) {
    const float* log_dt = (const float*)d_in[0];
    const float* w_re   = (const float*)d_in[1];
    const float* w_im   = (const float*)d_in[2];
    const float* B_re   = (const float*)d_in[3];
    const float* B_im   = (const float*)d_in[4];
    const float* P_re   = (const float*)d_in[5];
    const float* P_im   = (const float*)d_in[6];
    const float* C_re   = (const float*)d_in[7];
    const float* C_im   = (const float*)d_in[8];
    float* out = (float*)d_out;

    ssknplr_kernel<<<dim3(HH), dim3(NTHREADS), 0, stream>>>(
        log_dt, w_re, w_im, B_re, B_im, P_re, P_im, C_re, C_im, out);
}

// Round 6
// 39.447 us; speedup vs baseline: 2.2774x; 1.0037x over previous
//
#include <hip/hip_runtime.h>
#include <hip/hip_bf16.h>
#include <math.h>

// S4 SSKernelNPLR, two kernels:
//   pole_kernel: per-(h,n) pole params (10 scalars, dt-folded), DUPLICATED as
//     (v,v) float2 pairs -> d_ws. 80 B per pole, 2.62 MB total.
//   ssknplr_kernel<true>: main. Pole params read via BLOCK-UNIFORM pointer ->
//     s_load into SGPRs (scalar pipe, K$), used directly as the one SGPR
//     source of v_pk_fma_f32. Phase-2 LDS traffic = 0 (was the r5 bottleneck:
//     ~20k broadcast ds_read_b64 per CU through the shared LDS pipe).
//   phase 2: Cauchy + Woodbury at 2049 rfft nodes, packed fp32, bins
//     (tid, tid+1024) in the two halves of v2f regs. z = 2i*tan(pi*l/L).
//   phase 2.5: Hermitian recombination -> half-size complex spectrum
//   phase 3: in-LDS 2048-pt radix-2 DIF inverse FFT (natural in, bitrev out)
//   output: x[2m]=Re z[m]/M, x[2m+1]=Im z[m]/M, coalesced float2 stores.
// Fallback <false> (ws too small): r5 LDS-broadcast path.
// Dims hardcoded: H=512, N=64, R=1, CH=1, L=4096.

#define HH   512
#define NN   64
#define LLEN 4096
#define MM   2048      // half length
#define NTHREADS 1024
#define ZPAD(i) ((i) + ((i) >> 4))

typedef float v2f __attribute__((ext_vector_type(2)));

__device__ __forceinline__ void pole_vals(
    float dt, float wr, float wi, float Br, float Bi,
    float Pr, float Pi, float Cr, float Ci, float* vals)
{
    vals[0] = -wi;                     // -wi   (dim = 2t - wi)
    vals[1] = -wr;                     // nr
    vals[2] = wr * wr;                 // wr^2
    vals[3] = dt * (Br * Cr - Bi * Ci); // v00r
    vals[4] = dt * (Br * Ci + Bi * Cr); // v00i
    vals[5] = dt * (Br * Pr + Bi * Pi); // v01r  (B*conj(P))
    vals[6] = dt * (Bi * Pr - Br * Pi); // v01i
    vals[7] = dt * (Pr * Cr - Pi * Ci); // v10r
    vals[8] = dt * (Pr * Ci + Pi * Cr); // v10i
    vals[9] = dt * (Pr * Pr + Pi * Pi); // v11
}

__global__ __launch_bounds__(256) void pole_kernel(
    const float* __restrict__ log_dt,
    const float* __restrict__ w_re, const float* __restrict__ w_im,
    const float* __restrict__ B_re, const float* __restrict__ B_im,
    const float* __restrict__ P_re, const float* __restrict__ P_im,
    const float* __restrict__ C_re, const float* __restrict__ C_im,
    v2f* __restrict__ pp)
{
    const int g = blockIdx.x * 256 + threadIdx.x;   // (h,n) flat, 0..32767
    const int h = g >> 6;
    const float dt = expf(log_dt[h]);
    const float wr = w_re[g] * dt, wi = w_im[g] * dt;
    float vals[10];
    pole_vals(dt, wr, wi, B_re[g], B_im[g], P_re[g], P_im[g], C_re[g], C_im[g], vals);
    v2f* o = pp + (size_t)g * 10;
    #pragma unroll
    for (int j = 0; j < 10; ++j) o[j] = (v2f){vals[j], vals[j]};
}

template<bool GPP>
__global__ __launch_bounds__(NTHREADS, 8) void ssknplr_kernel(
    const float* __restrict__ log_dt,
    const float* __restrict__ w_re, const float* __restrict__ w_im,
    const float* __restrict__ B_re, const float* __restrict__ B_im,
    const float* __restrict__ P_re, const float* __restrict__ P_im,
    const float* __restrict__ C_re, const float* __restrict__ C_im,
    const v2f* __restrict__ pp,
    float* __restrict__ out)
{
    __shared__ float2 s_Z[ZPAD(MM) + 1];        // padded spectrum (~17.4 KB)
    __shared__ float2 s_tw[MM];                 // stage-major twiddles (16 KB)
    __shared__ v2f    s_pp[GPP ? 1 : NN * 10];  // fallback path only

    const int h   = blockIdx.x;
    const int tid = threadIdx.x;

    // block-uniform pole-param pointer (GPP path): loads become s_load -> SGPR
    const v2f* __restrict__ pg = pp + (size_t)h * (NN * 10);

    // ---- phase 1 ----
    if constexpr (!GPP) {
        if (tid < NN) {
            const int n   = tid;
            const int idx = h * NN + n;
            const float dt = expf(log_dt[h]);
            const float wr = w_re[idx] * dt, wi = w_im[idx] * dt;
            float vals[10];
            pole_vals(dt, wr, wi, B_re[idx], B_im[idx], P_re[idx], P_im[idx],
                      C_re[idx], C_im[idx], vals);
            #pragma unroll
            for (int j = 0; j < 10; ++j) s_pp[n * 10 + j] = (v2f){vals[j], vals[j]};
        }
    }
    // stage-major twiddles: entry (2^s - 1) + j holds e^{+2*pi*i*j / 2^{s+1}}
    for (int i = tid; i < MM - 1; i += NTHREADS) {
        const int v = i + 1;
        const int s = 31 - __clz(v);
        const int j = v - (1 << s);
        const float ang = (float)j * (3.14159265358979323846f / (float)(1 << s));
        float sj, cj;
        sincosf(ang, &sj, &cj);
        s_tw[i] = make_float2(cj, sj);
    }
    __syncthreads();

    // ---- phase 2: Cauchy + Woodbury, packed over bins (tid, tid+1024) ----
    const float pi_over_L = 3.14159265358979323846f / (float)LLEN;
    v2f tv;
    tv.x = tanf(pi_over_L * (float)tid);
    tv.y = tanf(pi_over_L * (float)(tid + MM / 2));
    const v2f t2v = tv + tv;

    v2f a00r = 0.f, a00i = 0.f, a01r = 0.f, a01i = 0.f;
    v2f a10r = 0.f, a10i = 0.f, a11r = 0.f, a11i = 0.f;

    for (int n = 0; n < NN; ++n) {
        v2f mwi, nr, wr2, v00r, v00i, v01r, v01i, v10r, v10i, v11;
        if constexpr (GPP) {
            mwi  = pg[n * 10 + 0]; nr   = pg[n * 10 + 1]; wr2 = pg[n * 10 + 2];
            v00r = pg[n * 10 + 3]; v00i = pg[n * 10 + 4];
            v01r = pg[n * 10 + 5]; v01i = pg[n * 10 + 6];
            v10r = pg[n * 10 + 7]; v10i = pg[n * 10 + 8];
            v11  = pg[n * 10 + 9];
        } else {
            mwi  = s_pp[n * 10 + 0]; nr   = s_pp[n * 10 + 1]; wr2 = s_pp[n * 10 + 2];
            v00r = s_pp[n * 10 + 3]; v00i = s_pp[n * 10 + 4];
            v01r = s_pp[n * 10 + 5]; v01i = s_pp[n * 10 + 6];
            v10r = s_pp[n * 10 + 7]; v10i = s_pp[n * 10 + 8];
            v11  = s_pp[n * 10 + 9];
        }
        const v2f dim = t2v + mwi;
        const v2f den = __builtin_elementwise_fma(dim, dim, wr2);
        v2f inv;
        inv.x = __builtin_amdgcn_rcpf(den.x);
        inv.y = __builtin_amdgcn_rcpf(den.y);
        const v2f ur = nr * inv;
        const v2f ui = -(dim * inv);
        a00r = __builtin_elementwise_fma( v00r, ur, a00r);
        a00r = __builtin_elementwise_fma(-v00i, ui, a00r);
        a00i = __builtin_elementwise_fma( v00r, ui, a00i);
        a00i = __builtin_elementwise_fma( v00i, ur, a00i);
        a01r = __builtin_elementwise_fma( v01r, ur, a01r);
        a01r = __builtin_elementwise_fma(-v01i, ui, a01r);
        a01i = __builtin_elementwise_fma( v01r, ui, a01i);
        a01i = __builtin_elementwise_fma( v01i, ur, a01i);
        a10r = __builtin_elementwise_fma( v10r, ur, a10r);
        a10r = __builtin_elementwise_fma(-v10i, ui, a10r);
        a10i = __builtin_elementwise_fma( v10r, ui, a10i);
        a10i = __builtin_elementwise_fma( v10i, ur, a10i);
        a11r = __builtin_elementwise_fma( v11,  ur, a11r);
        a11i = __builtin_elementwise_fma( v11,  ui, a11i);
    }

    {   // Woodbury + bilinear factor, packed; unpack on store.
        const v2f dr = a11r + 1.0f;
        const v2f di = a11i;
        const v2f dd = __builtin_elementwise_fma(dr, dr, di * di);
        v2f dinv;
        dinv.x = __builtin_amdgcn_rcpf(dd.x);
        dinv.y = __builtin_amdgcn_rcpf(dd.y);
        const v2f numr = a01r * a10r - a01i * a10i;
        const v2f numi = a01r * a10i + a01i * a10r;
        const v2f cr = (numr * dr + numi * di) * dinv;
        const v2f ci = (numi * dr - numr * di) * dinv;
        const v2f Wr = a00r - cr;
        const v2f Wi = a00i - ci;
        const v2f Kr = __builtin_elementwise_fma(-tv, Wi, Wr);
        const v2f Ki = __builtin_elementwise_fma( tv, Wr, Wi);
        // bin l=0: imaginary part unused in the real output
        s_Z[ZPAD(tid)] = make_float2(Kr.x, (tid == 0) ? 0.0f : Ki.x);
        s_Z[ZPAD(tid + MM / 2)] = make_float2(Kr.y, Ki.y);
    }
    // Nyquist bin K[M]: analytic z->inf limit, real part only
    if (tid == 0) {
        float sr = 0.f;
        if constexpr (GPP) {
            for (int n = 0; n < NN; ++n) sr += pg[n * 10 + 3].x;
        } else {
            for (int n = 0; n < NN; ++n) sr += s_pp[n * 10 + 3].x;
        }
        s_Z[ZPAD(MM)] = make_float2(0.5f * sr, 0.0f);
    }
    __syncthreads();

    // ---- phase 2.5: Hermitian recombination -> half-size spectrum (in place) ----
    {
        const float ang0 = 3.14159265358979323846f / (float)MM;   // 2*pi/L
        const int k = tid;                    // 0..1023
        if (k == 0) {
            const float a = s_Z[ZPAD(0)].x;
            const float b = s_Z[ZPAD(MM)].x;
            s_Z[ZPAD(0)] = make_float2(0.5f * (a + b), 0.5f * (a - b));
            const float2 km = s_Z[ZPAD(MM / 2)];
            s_Z[ZPAD(MM / 2)] = make_float2(km.x, -km.y);
        } else {
            const float2 Ka = s_Z[ZPAD(k)];
            const float2 Kb = s_Z[ZPAD(MM - k)];
            float sk, ck;
            sincosf((float)k * ang0, &sk, &ck);
            const float Pr = 0.5f * (Ka.x + Kb.x), Pi = 0.5f * (Ka.y - Kb.y);
            const float Dr = 0.5f * (Ka.x - Kb.x), Di = 0.5f * (Ka.y + Kb.y);
            const float al = sk * Dr + ck * Di;
            const float be = ck * Dr - sk * Di;
            s_Z[ZPAD(k)]      = make_float2(Pr - al, Pi + be);
            s_Z[ZPAD(MM - k)] = make_float2(Pr + al, be - Pi);
        }
    }
    __syncthreads();

    // ---- phase 3: 2048-pt inverse FFT, radix-2 DIF (natural in, bitrev out) ----
    for (int s = 10; s >= 1; --s) {
        const int half = 1 << s;
        const int b  = tid;                       // one butterfly per thread
        const int j  = b & (half - 1);
        const int i0 = ((b >> s) << (s + 1)) + j;
        const int i1 = i0 + half;
        const float2 w = s_tw[(half - 1) + j];
        const float2 u = s_Z[ZPAD(i0)];
        const float2 v = s_Z[ZPAD(i1)];
        s_Z[ZPAD(i0)] = make_float2(u.x + v.x, u.y + v.y);
        const float dx = u.x - v.x, dy = u.y - v.y;
        s_Z[ZPAD(i1)] = make_float2(dx * w.x - dy * w.y, dx * w.y + dy * w.x);
        __syncthreads();
    }
    {   // final stage s=0: twiddle = 1, pure add/sub
        const int i0 = tid << 1, i1 = i0 | 1;
        const float2 u = s_Z[ZPAD(i0)];
        const float2 v = s_Z[ZPAD(i1)];
        s_Z[ZPAD(i0)] = make_float2(u.x + v.x, u.y + v.y);
        s_Z[ZPAD(i1)] = make_float2(u.x - v.x, u.y - v.y);
    }
    __syncthreads();

    // ---- output: z[m] = Zfinal[bitrev(m)]; x[2m]=Re/M, x[2m+1]=Im/M ----
    const float scale = 1.0f / (float)MM;
    float2* o2 = (float2*)out + (size_t)h * MM;
    #pragma unroll
    for (int q = 0; q < 2; ++q) {
        const int m = tid + q * NTHREADS;
        const int r = (int)(__brev((unsigned)m) >> 21);
        const float2 z = s_Z[ZPAD(r)];
        o2[m] = make_float2(z.x * scale, z.y * scale);
    }
}

extern "C" void kernel_launch(void* const* d_in, const int* in_sizes, int n_in,
                              void* d_out, int out_size, void* d_ws, size_t ws_size,
                              hipStream_t stream) {
    const float* log_dt = (const float*)d_in[0];
    const float* w_re   = (const float*)d_in[1];
    const float* w_im   = (const float*)d_in[2];
    const float* B_re   = (const float*)d_in[3];
    const float* B_im   = (const float*)d_in[4];
    const float* P_re   = (const float*)d_in[5];
    const float* P_im   = (const float*)d_in[6];
    const float* C_re   = (const float*)d_in[7];
    const float* C_im   = (const float*)d_in[8];
    float* out = (float*)d_out;

    const size_t pp_bytes = (size_t)HH * NN * 10 * sizeof(v2f);   // 2.62 MB
    if (ws_size >= pp_bytes) {
        v2f* pp = (v2f*)d_ws;
        pole_kernel<<<dim3(HH * NN / 256), dim3(256), 0, stream>>>(
            log_dt, w_re, w_im, B_re, B_im, P_re, P_im, C_re, C_im, pp);
        ssknplr_kernel<true><<<dim3(HH), dim3(NTHREADS), 0, stream>>>(
            log_dt, w_re, w_im, B_re, B_im, P_re, P_im, C_re, C_im, pp, out);
    } else {
        ssknplr_kernel<false><<<dim3(HH), dim3(NTHREADS), 0, stream>>>(
            log_dt, w_re, w_im, B_re, B_im, P_re, P_im, C_re, C_im,
            (const v2f*)d_ws, out);
    }
}

// Round 7
// 38.090 us; speedup vs baseline: 2.3585x; 1.0356x over previous
//
#include <hip/hip_runtime.h>
#include <hip/hip_bf16.h>
#include <math.h>

// S4 SSKernelNPLR, fully fused per-head (single kernel):
//   phase 1: per-h pole params (10 scalars, dt-folded), duplicated as (v,v)
//            float2 pairs in LDS -> phase-2 operands are ds_read b64/b128.
//   phase 2: Cauchy + Woodbury at 2049 rfft nodes, packed fp32
//            (v_pk_fma_f32), bins (tid, tid+1024) in the halves of v2f regs.
//            z = 2i*tan(pi*l/L); tan via HW v_sin/v_cos (revolution args,
//            all < 0.25 -> no range reduction); ONE v_rcp per pole via
//            rcp(den.x*den.y) + swap-mul.
//   phase 2.5: Hermitian recombination -> half-size complex spectrum
//   phase 3: 2048-pt radix-2 DIF inverse FFT, TWO stages fused per barrier
//            (4 pts/thread in regs; level-B twiddle = wA^2), twiddles
//            computed on the fly with HW sin/cos -> NO twiddle table.
//   output: x[2m]=Re z[m]/M, x[2m+1]=Im z[m]/M, coalesced float2 stores.
//
// 1024 thr/block, 2 blocks/CU (thread-capped), __launch_bounds__(1024,8).
// ZPAD kills stride-2^k bank conflicts. LDS ~22.5 KB.
// Dims hardcoded: H=512, N=64, R=1, CH=1, L=4096.

#define HH   512
#define NN   64
#define LLEN 4096
#define MM   2048      // half length
#define NTHREADS 1024
#define ZPAD(i) ((i) + ((i) >> 4))

typedef float v2f __attribute__((ext_vector_type(2)));

__global__ __launch_bounds__(NTHREADS, 8) void ssknplr_kernel(
    const float* __restrict__ log_dt,
    const float* __restrict__ w_re, const float* __restrict__ w_im,
    const float* __restrict__ B_re, const float* __restrict__ B_im,
    const float* __restrict__ P_re, const float* __restrict__ P_im,
    const float* __restrict__ C_re, const float* __restrict__ C_im,
    float* __restrict__ out)
{
    // per-pole duplicated scalars: [0]=-wi [1]=-wr [2]=wr^2
    // [3]=v00r [4]=v00i [5]=v01r [6]=v01i [7]=v10r [8]=v10i [9]=v11 (all *dt)
    __shared__ v2f    s_pp[NN][10];        // 5 KB
    __shared__ float2 s_Z[ZPAD(MM) + 1];   // ~17.4 KB padded spectrum

    const int h   = blockIdx.x;
    const int tid = threadIdx.x;

    // ---- phase 1: per-head pole data (duplicated halves) ----
    if (tid < NN) {
        const int n   = tid;
        const int idx = h * NN + n;
        const float dt = expf(log_dt[h]);
        const float wr = w_re[idx] * dt;
        const float wi = w_im[idx] * dt;
        const float Br = B_re[idx], Bi = B_im[idx];
        const float Pr = P_re[idx], Pi = P_im[idx];
        const float Cr = C_re[idx], Ci = C_im[idx];
        const float vals[10] = {
            -wi, -wr, wr * wr,
            dt * (Br * Cr - Bi * Ci),   // v00r
            dt * (Br * Ci + Bi * Cr),   // v00i
            dt * (Br * Pr + Bi * Pi),   // v01r  (B*conj(P))
            dt * (Bi * Pr - Br * Pi),   // v01i
            dt * (Pr * Cr - Pi * Ci),   // v10r
            dt * (Pr * Ci + Pi * Cr),   // v10i
            dt * (Pr * Pr + Pi * Pi)    // v11
        };
        #pragma unroll
        for (int j = 0; j < 10; ++j) s_pp[n][j] = (v2f){vals[j], vals[j]};
    }
    __syncthreads();

    // ---- phase 2: Cauchy + Woodbury, packed over bins (tid, tid+1024) ----
    // t = tan(pi*l/L) = sin(2*pi*rev)/cos(2*pi*rev), rev = l/8192 < 0.25
    v2f tv;
    {
        const float rx = (float)tid * (1.0f / 8192.0f);
        const float ry = (float)(tid + 1024) * (1.0f / 8192.0f);
        tv.x = __builtin_amdgcn_sinf(rx) * __builtin_amdgcn_rcpf(__builtin_amdgcn_cosf(rx));
        tv.y = __builtin_amdgcn_sinf(ry) * __builtin_amdgcn_rcpf(__builtin_amdgcn_cosf(ry));
    }
    const v2f t2v = tv + tv;

    v2f a00r = 0.f, a00i = 0.f, a01r = 0.f, a01i = 0.f;
    v2f a10r = 0.f, a10i = 0.f, a11r = 0.f, a11i = 0.f;

    for (int n = 0; n < NN; ++n) {
        const v2f mwi  = s_pp[n][0];
        const v2f nr   = s_pp[n][1];
        const v2f wr2  = s_pp[n][2];
        const v2f dim = t2v + mwi;
        const v2f den = __builtin_elementwise_fma(dim, dim, wr2);
        // one rcp for both halves: 1/den.x = den.y*ip, 1/den.y = den.x*ip
        const float ip = __builtin_amdgcn_rcpf(den.x * den.y);
        const v2f dsw = __builtin_shufflevector(den, den, 1, 0);
        const v2f inv = dsw * (v2f){ip, ip};
        const v2f ur = nr * inv;
        const v2f ui = -(dim * inv);
        const v2f v00r = s_pp[n][3], v00i = s_pp[n][4];
        const v2f v01r = s_pp[n][5], v01i = s_pp[n][6];
        const v2f v10r = s_pp[n][7], v10i = s_pp[n][8];
        const v2f v11  = s_pp[n][9];
        a00r = __builtin_elementwise_fma( v00r, ur, a00r);
        a00r = __builtin_elementwise_fma(-v00i, ui, a00r);
        a00i = __builtin_elementwise_fma( v00r, ui, a00i);
        a00i = __builtin_elementwise_fma( v00i, ur, a00i);
        a01r = __builtin_elementwise_fma( v01r, ur, a01r);
        a01r = __builtin_elementwise_fma(-v01i, ui, a01r);
        a01i = __builtin_elementwise_fma( v01r, ui, a01i);
        a01i = __builtin_elementwise_fma( v01i, ur, a01i);
        a10r = __builtin_elementwise_fma( v10r, ur, a10r);
        a10r = __builtin_elementwise_fma(-v10i, ui, a10r);
        a10i = __builtin_elementwise_fma( v10r, ui, a10i);
        a10i = __builtin_elementwise_fma( v10i, ur, a10i);
        a11r = __builtin_elementwise_fma( v11,  ur, a11r);
        a11i = __builtin_elementwise_fma( v11,  ui, a11i);
    }

    {   // Woodbury + bilinear factor, packed; unpack on store.
        const v2f dr = a11r + 1.0f;
        const v2f di = a11i;
        const v2f dd = __builtin_elementwise_fma(dr, dr, di * di);
        v2f dinv;
        dinv.x = __builtin_amdgcn_rcpf(dd.x);
        dinv.y = __builtin_amdgcn_rcpf(dd.y);
        const v2f numr = a01r * a10r - a01i * a10i;
        const v2f numi = a01r * a10i + a01i * a10r;
        const v2f cr = (numr * dr + numi * di) * dinv;
        const v2f ci = (numi * dr - numr * di) * dinv;
        const v2f Wr = a00r - cr;
        const v2f Wi = a00i - ci;
        const v2f Kr = __builtin_elementwise_fma(-tv, Wi, Wr);
        const v2f Ki = __builtin_elementwise_fma( tv, Wr, Wi);
        // bin l=0: imaginary part unused in the real output
        s_Z[ZPAD(tid)] = make_float2(Kr.x, (tid == 0) ? 0.0f : Ki.x);
        s_Z[ZPAD(tid + 1024)] = make_float2(Kr.y, Ki.y);
    }
    // Nyquist bin K[M]: analytic z->inf limit, real part only
    if (tid == 0) {
        float sr = 0.f;
        for (int n = 0; n < NN; ++n) sr += s_pp[n][3].x;
        s_Z[ZPAD(MM)] = make_float2(0.5f * sr, 0.0f);
    }
    __syncthreads();

    // ---- phase 2.5: Hermitian recombination -> half-size spectrum (in place) ----
    {
        const int k = tid;                    // 0..1023
        if (k == 0) {
            const float a = s_Z[ZPAD(0)].x;
            const float b = s_Z[ZPAD(MM)].x;
            s_Z[ZPAD(0)] = make_float2(0.5f * (a + b), 0.5f * (a - b));
            const float2 km = s_Z[ZPAD(MM / 2)];
            s_Z[ZPAD(MM / 2)] = make_float2(km.x, -km.y);
        } else {
            const float2 Ka = s_Z[ZPAD(k)];
            const float2 Kb = s_Z[ZPAD(MM - k)];
            const float rk = (float)k * (1.0f / 4096.0f);   // revolutions, < 0.25
            const float sk = __builtin_amdgcn_sinf(rk);
            const float ck = __builtin_amdgcn_cosf(rk);
            const float Pr = 0.5f * (Ka.x + Kb.x), Pi = 0.5f * (Ka.y - Kb.y);
            const float Dr = 0.5f * (Ka.x - Kb.x), Di = 0.5f * (Ka.y + Kb.y);
            const float al = sk * Dr + ck * Di;
            const float be = ck * Dr - sk * Di;
            s_Z[ZPAD(k)]      = make_float2(Pr - al, Pi + be);
            s_Z[ZPAD(MM - k)] = make_float2(Pr + al, be - Pi);
        }
    }
    __syncthreads();

    // ---- phase 3: 2048-pt inverse FFT, radix-2 DIF, TWO stages per barrier ----
    // Stage s (half H) then stage s-1 (half H/2) on 4 register-resident points
    // {base, base+H/2, base+H, base+3H/2}. Stage-s twiddles: wA(j), i*wA(j);
    // stage-(s-1) twiddle: wB = wA^2.  wA = e^{+2*pi*i*j/(2H)}.
    for (int s = 10; s >= 1; s -= 2) {
        const int H = 1 << s;
        const int Q = H >> 1;
        const float scale = __builtin_amdgcn_rcpf((float)(2 * H));  // exact pow2
        if (tid < 512) {
            const int b    = tid;
            const int j    = b & (Q - 1);
            const int base = ((b >> (s - 1)) << (s + 1)) + j;
            const int i0 = base, i1 = base + Q, i2 = base + H, i3 = base + H + Q;
            const float rev = (float)j * scale;                 // < 0.25
            const float c  = __builtin_amdgcn_cosf(rev);
            const float sn = __builtin_amdgcn_sinf(rev);
            const float wbr = c * c - sn * sn;                  // wB = wA^2
            const float wbi = 2.0f * c * sn;
            const float2 u0 = s_Z[ZPAD(i0)];
            const float2 u1 = s_Z[ZPAD(i1)];
            const float2 u2 = s_Z[ZPAD(i2)];
            const float2 u3 = s_Z[ZPAD(i3)];
            // level A (stage s): (i0,i2) with wA ; (i1,i3) with i*wA
            const float a0r = u0.x + u2.x, a0i = u0.y + u2.y;
            const float d0r = u0.x - u2.x, d0i = u0.y - u2.y;
            const float a1r = u1.x + u3.x, a1i = u1.y + u3.y;
            const float d1r = u1.x - u3.x, d1i = u1.y - u3.y;
            const float e0r = d0r * c  - d0i * sn, e0i = d0r * sn + d0i * c;
            const float e1r = -(d1r * sn) - d1i * c, e1i = d1r * c - d1i * sn;
            // level B (stage s-1): (i0,i1) and (i2,i3), both with wB
            s_Z[ZPAD(i0)] = make_float2(a0r + a1r, a0i + a1i);
            const float t0r = a0r - a1r, t0i = a0i - a1i;
            s_Z[ZPAD(i1)] = make_float2(t0r * wbr - t0i * wbi, t0r * wbi + t0i * wbr);
            s_Z[ZPAD(i2)] = make_float2(e0r + e1r, e0i + e1i);
            const float t1r = e0r - e1r, t1i = e0i - e1i;
            s_Z[ZPAD(i3)] = make_float2(t1r * wbr - t1i * wbi, t1r * wbi + t1i * wbr);
        }
        __syncthreads();
    }
    {   // final stage s=0: twiddle = 1, pure add/sub, all 1024 threads
        const int i0 = tid << 1, i1 = i0 | 1;
        const float2 u = s_Z[ZPAD(i0)];
        const float2 v = s_Z[ZPAD(i1)];
        s_Z[ZPAD(i0)] = make_float2(u.x + v.x, u.y + v.y);
        s_Z[ZPAD(i1)] = make_float2(u.x - v.x, u.y - v.y);
    }
    __syncthreads();

    // ---- output: z[m] = Zfinal[bitrev(m)]; x[2m]=Re/M, x[2m+1]=Im/M ----
    const float scale = 1.0f / (float)MM;
    float2* o2 = (float2*)out + (size_t)h * MM;
    #pragma unroll
    for (int q = 0; q < 2; ++q) {
        const int m = tid + q * NTHREADS;
        const int r = (int)(__brev((unsigned)m) >> 21);
        const float2 z = s_Z[ZPAD(r)];
        o2[m] = make_float2(z.x * scale, z.y * scale);
    }
}

extern "C" void kernel_launch(void* const* d_in, const int* in_sizes, int n_in,
                              void* d_out, int out_size, void* d_ws, size_t ws_size,
                              hipStream_t stream) {
    const float* log_dt = (const float*)d_in[0];
    const float* w_re   = (const float*)d_in[1];
    const float* w_im   = (const float*)d_in[2];
    const float* B_re   = (const float*)d_in[3];
    const float* B_im   = (const float*)d_in[4];
    const float* P_re   = (const float*)d_in[5];
    const float* P_im   = (const float*)d_in[6];
    const float* C_re   = (const float*)d_in[7];
    const float* C_im   = (const float*)d_in[8];
    float* out = (float*)d_out;

    ssknplr_kernel<<<dim3(HH), dim3(NTHREADS), 0, stream>>>(
        log_dt, w_re, w_im, B_re, B_im, P_re, P_im, C_re, C_im, out);
}